// Round 10
// baseline (689.471 us; speedup 1.0000x reference)
//
#include <hip/hip_runtime.h>

#define B_ 8
#define CQ_ 256
#define CKV_ 512
#define N_ 4096
#define DQK_ 32
#define LOG2E 1.44269504f

typedef __bf16 bf16;
typedef __bf16 bf16x4 __attribute__((ext_vector_type(4)));
typedef __bf16 bf16x8 __attribute__((ext_vector_type(8)));
typedef float f32x4 __attribute__((ext_vector_type(4)));

// ---------------- weight convert fp32 -> bf16 (Wq pre-scaled by log2e) ----------------
__global__ void k_convert_w(const float* __restrict__ Wq, const float* __restrict__ Wk,
                            const float* __restrict__ Wv,
                            bf16* __restrict__ wq, bf16* __restrict__ wk, bf16* __restrict__ wv) {
    int i = blockIdx.x * 256 + threadIdx.x;
    if (i < 8192) wq[i] = (bf16)(Wq[i] * LOG2E);
    else if (i < 24576) wk[i - 8192] = (bf16)Wk[i - 8192];
    else if (i < 155648) wv[i - 24576] = (bf16)Wv[i - 24576];
}

// ---------------- bilinear resize 32x32 -> 64x64, transposed to [b][n][u] ----------------
__global__ __launch_bounds__(256) void k_resize(const float* __restrict__ kv, bf16* __restrict__ kvr) {
    const int yo = blockIdx.x;   // output row 0..63
    const int b  = blockIdx.y;
    const int uc = blockIdx.z * 64;
    const int tid = threadIdx.x;
    __shared__ float r0[64][33];
    __shared__ float r1[64][33];
    int ty = yo >> 1;
    int y0, y1; float wy0, wy1;
    if ((yo & 1) == 0) { y0 = ty > 0 ? ty - 1 : 0; y1 = ty; wy0 = 0.25f; wy1 = 0.75f; }
    else               { y0 = ty; y1 = ty < 31 ? ty + 1 : 31; wy0 = 0.75f; wy1 = 0.25f; }
    const int u_loc = tid & 63;
    const int xo_base = tid >> 6;
    for (int i = 0; i < 8; ++i) {
        int idx = tid + i * 256;
        int u = idx >> 5, x = idx & 31;
        const float* src = kv + ((size_t)b * CKV_ + uc + u) * 1024 + x;
        r0[u][x] = src[y0 * 32];
        r1[u][x] = src[y1 * 32];
    }
    __syncthreads();
    for (int i = 0; i < 16; ++i) {
        int xo = xo_base + i * 4;
        int tx = xo >> 1;
        int xa, xb; float wxa, wxb;
        if ((xo & 1) == 0) { xa = tx > 0 ? tx - 1 : 0; xb = tx; wxa = 0.25f; wxb = 0.75f; }
        else               { xa = tx; xb = tx < 31 ? tx + 1 : 31; wxa = 0.75f; wxb = 0.25f; }
        float v0 = wxa * r0[u_loc][xa] + wxb * r0[u_loc][xb];
        float v1 = wxa * r1[u_loc][xa] + wxb * r1[u_loc][xb];
        float val = wy0 * v0 + wy1 * v1;
        kvr[((size_t)b * N_ + yo * 64 + xo) * CKV_ + uc + u_loc] = (bf16)val;
    }
}

// ---------------- fused: transpose query tile to LDS + q projection ----------------
__global__ __launch_bounds__(256) void k_proj_q_fused(const float* __restrict__ query,
                                                      const bf16* __restrict__ W,     // [32][256] (pre-scaled)
                                                      const float* __restrict__ bias, // [32]
                                                      bf16* __restrict__ qTb) {       // [B][N][32]
    __shared__ bf16 tile[64][264];
    const int n0 = blockIdx.x * 64;
    const int b  = blockIdx.y;
    const int tid = threadIdx.x;
    const int xi = tid & 15, c0 = tid >> 4;
    for (int pass = 0; pass < 16; ++pass) {
        int c = c0 + pass * 16;
        const float4 v = *(const float4*)(query + ((size_t)b * CQ_ + c) * N_ + n0 + xi * 4);
        tile[xi * 4 + 0][c] = (bf16)v.x;
        tile[xi * 4 + 1][c] = (bf16)v.y;
        tile[xi * 4 + 2][c] = (bf16)v.z;
        tile[xi * 4 + 3][c] = (bf16)v.w;
    }
    __syncthreads();
    const int w = tid >> 6, lane = tid & 63;
    const int l16 = lane & 15, quad = lane >> 4;
    const int ct = w & 1, nh = w >> 1;
    f32x4 acc[2];
    acc[0] = (f32x4){0.f, 0.f, 0.f, 0.f}; acc[1] = (f32x4){0.f, 0.f, 0.f, 0.f};
    const bf16* aptr = W + (ct * 16 + l16) * CQ_ + quad * 8;
#pragma unroll
    for (int ks = 0; ks < 8; ++ks) {
        bf16x8 af = *(const bf16x8*)(aptr + ks * 32);
        for (int j = 0; j < 2; ++j) {
            bf16x8 bfv = *(const bf16x8*)&tile[nh * 32 + j * 16 + l16][ks * 32 + quad * 8];
            acc[j] = __builtin_amdgcn_mfma_f32_16x16x32_bf16(af, bfv, acc[j], 0, 0, 0);
        }
    }
    for (int j = 0; j < 2; ++j)
        for (int r = 0; r < 4; ++r) {
            int d = ct * 16 + quad * 4 + r;
            int n = n0 + nh * 32 + j * 16 + l16;
            qTb[((size_t)b * N_ + n) * DQK_ + d] = (bf16)(acc[j][r] + bias[d] * LOG2E);
        }
}

// ---------------- k projection (32-m blocks) ----------------
__global__ __launch_bounds__(256) void k_proj_k(const bf16* __restrict__ W,
                                                const float* __restrict__ bias,
                                                const bf16* __restrict__ Bm,
                                                bf16* __restrict__ outT) {
    const int flat = blockIdx.x + 128 * blockIdx.y;
    const int b  = flat & 7;
    const int mb = (flat >> 3) * 32;
    const int tid = threadIdx.x;
    const int w = tid >> 6, lane = tid & 63;
    const int l16 = lane & 15, quad = lane >> 4;
    const int ct = w & 1;
    const int mh = (w >> 1) * 16;
    f32x4 acc = (f32x4){0.f, 0.f, 0.f, 0.f};
    const bf16* aptr = W + (ct * 16 + l16) * CKV_ + quad * 8;
    const bf16* bptr = Bm + ((size_t)b * N_ + mb + mh + l16) * CKV_ + quad * 8;
#pragma unroll
    for (int ks = 0; ks < 16; ++ks) {
        bf16x8 af  = *(const bf16x8*)(aptr + ks * 32);
        bf16x8 bfv = *(const bf16x8*)(bptr + ks * 32);
        acc = __builtin_amdgcn_mfma_f32_16x16x32_bf16(af, bfv, acc, 0, 0, 0);
    }
    const int m = mb + mh + l16;
    for (int r = 0; r < 4; ++r) {
        int d = ct * 16 + quad * 4 + r;
        outT[((size_t)b * N_ + m) * DQK_ + d] = (bf16)(acc[r] + bias[d]);
    }
}

// ---------------- v projection (32-m blocks) ----------------
__global__ __launch_bounds__(256) void k_proj_v(const bf16* __restrict__ W,
                                                const float* __restrict__ bias,
                                                const bf16* __restrict__ Bm,
                                                bf16* __restrict__ vout) {
    const int flat = blockIdx.x + 128 * blockIdx.y;
    const int b  = flat & 7;
    const int mb = (flat >> 3) * 32;
    const int tid = threadIdx.x;
    const int w = tid >> 6, lane = tid & 63;
    const int l16 = lane & 15, quad = lane >> 4;
    f32x4 acc[4][2];
    for (int i = 0; i < 4; ++i) for (int j = 0; j < 2; ++j) acc[i][j] = (f32x4){0.f, 0.f, 0.f, 0.f};
    const bf16* bbase = Bm + ((size_t)b * N_ + mb) * CKV_ + quad * 8;
#pragma unroll 4
    for (int ks = 0; ks < 16; ++ks) {
        bf16x8 bfv[2];
        for (int j = 0; j < 2; ++j)
            bfv[j] = *(const bf16x8*)(bbase + (size_t)(j * 16 + l16) * CKV_ + ks * 32);
        for (int i = 0; i < 4; ++i) {
            bf16x8 af = *(const bf16x8*)(W + (size_t)((w * 4 + i) * 16 + l16) * CKV_ + ks * 32 + quad * 8);
            for (int j = 0; j < 2; ++j)
                acc[i][j] = __builtin_amdgcn_mfma_f32_16x16x32_bf16(af, bfv[j], acc[i][j], 0, 0, 0);
        }
    }
    for (int i = 0; i < 4; ++i)
        for (int r = 0; r < 4; ++r) {
            int c = (w * 4 + i) * 16 + quad * 4 + r;
            float bvs = bias[c];
            for (int j = 0; j < 2; ++j) {
                int m = mb + j * 16 + l16;
                vout[((size_t)b * CQ_ + c) * N_ + m] = (bf16)(acc[i][j][r] + bvs);
            }
        }
}

// ---------------- flash attention: BARRIER-FREE + c-split (redundancy 2) ----------------
// Synthesis of the two measured wins: r0's wave-private P (zero __syncthreads;
// DS in-order per wave) and r9's c-split (S redundancy 2, not r0's 4). Each
// wave owns 16 n-cols x 128 channels: S = 4 swapped-operand MFMAs + 16 exps,
// P round-trips through a PRIVATE single-buffer LDS row-set (write then read
// in program order -> in-order DS makes it safe, no barrier anywhere); PV = 16
// MFMAs over 8 c-tiles. Denominator fully wave-local (shfl). Register budget
// engineered for the <=128 HW bin (r8 lesson: (128,256] pins 2 waves/SIMD):
// acc 32 + vf0 32 + vf1 32 (staggered issue) + kf 16 + q 4 ~= 120 ->
// 4 waves/SIMD, 4 blocks/CU, LDS 9.2KB/block. vf0(u+1) issued at the bottom
// of iter u so S(u+1) hides its latency. Batch<->XCD remap kept.
__global__ __launch_bounds__(256) void k_flash(const bf16* __restrict__ qT,   // [B][N][32]
                                               const bf16* __restrict__ kT,   // [B][N][32]
                                               const bf16* __restrict__ vv,   // [B][256][N]
                                               const float* __restrict__ query,
                                               const float* __restrict__ gamma,
                                               float* __restrict__ out) {
    __shared__ bf16 P[4][16][72];   // wave-private, single buffer: 9,216 B
    const int z = blockIdx.z;       // channel half: c in [z*128, z*128+128)
    const int tid = threadIdx.x;
    const int w = tid >> 6, lane = tid & 63;
    const int l16 = lane & 15, quad = lane >> 4;
    const int swz = l16 & 3;
    // batch<->XCD remap: linear block id % 8 == x % 8 == b for all y,z
    const int flat = blockIdx.x + 64 * blockIdx.y;
    const int b  = flat & 7;
    const int n0 = (flat >> 3) * 64;
    const int nw = n0 + w * 16;     // this wave's 16 n-cols

    // Q fragment (B-operand), loop-invariant: n = nw + l16
    const bf16x8 qfrag = *(const bf16x8*)(qT + ((size_t)b * N_ + nw + l16) * DQK_ + quad * 8);

    f32x4 acc[8];   // c-tile i: c = z*128 + i*16 + quad*4 + r, n = nw + l16
#pragma unroll
    for (int i = 0; i < 8; ++i) acc[i] = (f32x4){0.f, 0.f, 0.f, 0.f};
    f32x4 lsum = (f32x4){0.f, 0.f, 0.f, 0.f};

    const bf16* kbase = kT + (size_t)b * N_ * DQK_;
    const bf16* vbase = vv + ((size_t)b * CQ_ + z * 128) * N_ + (size_t)l16 * N_ + quad * 8;

    bf16 (* __restrict__ Pw)[72] = P[w];
    const int roff0 = ((((0 << 1) | (quad >> 1)) ^ swz) << 4) + ((quad & 1) << 3);
    const int roff1 = ((((1 << 1) | (quad >> 1)) ^ swz) << 4) + ((quad & 1) << 3);

    auto loadK = [&](int mt, bf16x8* dst) {
        for (int im = 0; im < 4; ++im)
            dst[im] = *(const bf16x8*)(kbase + (size_t)(mt * 64 + im * 16 + l16) * DQK_ + quad * 8);
    };
    auto loadV = [&](int m0, int ks, bf16x8* dst) {   // 8 c-tiles, one ks half
        for (int i = 0; i < 8; ++i)
            dst[i] = *(const bf16x8*)(vbase + (size_t)i * (16 * N_) + m0 + ks * 32);
    };

    // prologue
    bf16x8 kf[4];
    loadK(0, kf);
    bf16x8 vf0[8];
    loadV(0, 0, vf0);

    for (int u = 0; u < 64; ++u) {
        const int m0 = u * 64;
        // S(u): 4 swapped-operand MFMAs, exp2 (log2e pre-folded), private P write.
        // D: col(l16)=n, row(quad*4+r)=m_local.
        for (int im = 0; im < 4; ++im) {
            f32x4 s = __builtin_amdgcn_mfma_f32_16x16x32_bf16(kf[im], qfrag,
                                                              (f32x4){0.f, 0.f, 0.f, 0.f}, 0, 0, 0);
            bf16x4 pk;
            for (int r = 0; r < 4; ++r) {
                float p = exp2f(s[r]);
                lsum[r] += p;
                pk[r] = (bf16)p;
            }
            *(bf16x4*)&Pw[l16][((im ^ swz) << 4) + quad * 4] = pk;
        }
        loadK((u + 1) & 63, kf);            // K(u+1) (dead wrap at end)
        // vf1 issued here: PV-ks0 (below) covers most of its latency
        bf16x8 vf1[8];
        loadV(m0, 1, vf1);
        // PV ks=0 (vf0 preloaded last iter; P read is in-order after writes)
        bf16x8 pf0 = *(const bf16x8*)&Pw[l16][roff0];
        __builtin_amdgcn_s_setprio(1);
        for (int i = 0; i < 8; ++i)
            acc[i] = __builtin_amdgcn_mfma_f32_16x16x32_bf16(vf0[i], pf0, acc[i], 0, 0, 0);
        __builtin_amdgcn_s_setprio(0);
        // PV ks=1
        bf16x8 pf1 = *(const bf16x8*)&Pw[l16][roff1];
        __builtin_amdgcn_s_setprio(1);
        for (int i = 0; i < 8; ++i)
            acc[i] = __builtin_amdgcn_mfma_f32_16x16x32_bf16(vf1[i], pf1, acc[i], 0, 0, 0);
        __builtin_amdgcn_s_setprio(0);
        // vf0 for next iter: S(u+1) hides the latency (dead wrap at end)
        loadV(((u + 1) & 63) * 64, 0, vf0);
    }

    // softmax denominator: lanes l16+16k share n -> quad shfl reduce, fully wave-local
    float s = (lsum[0] + lsum[1]) + (lsum[2] + lsum[3]);
    s += __shfl_xor(s, 16);
    s += __shfl_xor(s, 32);
    const float linv = 1.f / s;
    const float g = gamma[0];
    const int n = nw + l16;
#pragma unroll
    for (int i = 0; i < 8; ++i)
        for (int r = 0; r < 4; ++r) {
            int c = z * 128 + i * 16 + quad * 4 + r;
            size_t idx = ((size_t)b * CQ_ + c) * N_ + n;
            out[idx] = g * acc[i][r] * linv + query[idx];
        }
}

extern "C" void kernel_launch(void* const* d_in, const int* in_sizes, int n_in,
                              void* d_out, int out_size, void* d_ws, size_t ws_size,
                              hipStream_t stream) {
    const float* query     = (const float*)d_in[0];
    const float* key_value = (const float*)d_in[1];
    const float* Wq = (const float*)d_in[2];
    const float* bq = (const float*)d_in[3];
    const float* Wk = (const float*)d_in[4];
    const float* bk = (const float*)d_in[5];
    const float* Wv = (const float*)d_in[6];
    const float* bv = (const float*)d_in[7];
    const float* gamma = (const float*)d_in[8];
    float* out = (float*)d_out;

    char* ws = (char*)d_ws;
    bf16* kvr  = (bf16*)(ws);              // [8][4096][512]  33,554,432 B
    bf16* vbuf = (bf16*)(ws + 33554432);   // [8][256][4096]  16,777,216 B
    bf16* qTb  = (bf16*)(ws + 50331648);   // [8][4096][32]    2,097,152 B
    bf16* kTb  = (bf16*)(ws + 52428800);   // [8][4096][32]    2,097,152 B
    bf16* wqb  = (bf16*)(ws + 54525952);   // [32][256]           16,384 B
    bf16* wkb  = (bf16*)(ws + 54542336);   // [32][512]           32,768 B
    bf16* wvb  = (bf16*)(ws + 54575104);   // [256][512]         262,144 B

    k_convert_w<<<608, 256, 0, stream>>>(Wq, Wk, Wv, wqb, wkb, wvb);
    k_resize<<<dim3(64, 8, 8), 256, 0, stream>>>(key_value, kvr);
    k_proj_q_fused<<<dim3(64, 8), 256, 0, stream>>>(query, wqb, bq, qTb);
    k_proj_k<<<dim3(128, 8), 256, 0, stream>>>(wkb, bk, kvr, kTb);
    k_proj_v<<<dim3(128, 8), 256, 0, stream>>>(wvb, bv, kvr, vbuf);
    k_flash<<<dim3(64, 8, 2), 256, 0, stream>>>(qTb, kTb, vbuf, query, gamma, out);
}